// Round 1
// baseline (219.086 us; speedup 1.0000x reference)
//
#include <hip/hip_runtime.h>

// Causal scaled-dot-product attention, B=8, S=2048, D=128, fp32 in/out.
// Flash-attention (online softmax), f16 MFMA 16x16x16.
//
// Layout trick: compute S^T = K*Q^T. Its C/D register layout
// (col=lane&15=q, row=quad*4+reg=key) EQUALS the B-operand layout
// (n=lane&15, k=quad*4+j) needed for O^T += V^T * P^T, so softmaxed
// probabilities go straight from MFMA output regs into the PV MFMA.
// Softmax stats are per-lane (lane&15 = query), replicated across quads.

#define BATCH 8
#define SEQ   2048
#define DIM   128

typedef _Float16 v2h __attribute__((ext_vector_type(2)));
typedef _Float16 v4h __attribute__((ext_vector_type(4)));
typedef _Float16 v8h __attribute__((ext_vector_type(8)));
typedef float    v4f __attribute__((ext_vector_type(4)));

__global__ __launch_bounds__(128) void attn_fwd(
    const float* __restrict__ Q, const float* __restrict__ K,
    const float* __restrict__ V, float* __restrict__ O)
{
    const int batch = blockIdx.x & 7;    // batch -> XCD locality (round-robin dispatch)
    const int qb    = blockIdx.x >> 3;   // 0..63, 32 query rows per WG
    const int tid   = threadIdx.x;
    const int wave  = tid >> 6;          // 0..1
    const int lane  = tid & 63;
    const int n     = lane & 15;         // q index in S^T cols / d_local in V^T frags
    const int quad  = lane >> 4;

    const int q0      = qb * 32 + wave * 16;   // this wave's 16-row q tile
    const int my_last = qb * 2 + wave;         // last k-tile (== q0/16, diagonal)
    const int nt      = qb * 2 + 2;            // k-tiles staged by this WG

    const size_t bo = (size_t)batch * SEQ * DIM;

    // K tile 16x128 f16, stride 136 (272B rows: 16B-aligned, 2-way banks = free)
    __shared__ __align__(16) _Float16 Ks[16 * 136];
    // V^T tile 128x16 f16, stride 20 (40B rows: 8B-aligned b64 reads, ~2-way banks)
    __shared__ __align__(16) _Float16 Vt[128 * 20];

    constexpr float kScale = 0.08838834764831845f;  // 1/sqrt(128)

    // Preload Q fragments (B operand of S^T MFMA): Q[q0+n][dc*16 + quad*4 + j]
    v4h qf[8];
    {
        const float* qp = Q + bo + (size_t)(q0 + n) * DIM + quad * 4;
        #pragma unroll
        for (int dc = 0; dc < 8; ++dc) {
            v4f qv = *(const v4f*)(qp + dc * 16);
            v4h h;
            #pragma unroll
            for (int i = 0; i < 4; ++i) h[i] = (_Float16)(qv[i] * kScale);
            qf[dc] = h;
        }
    }

    float m_run = -1e30f, l_run = 0.0f;
    v4f of[8];
    #pragma unroll
    for (int dc = 0; dc < 8; ++dc) of[dc] = (v4f){0.f, 0.f, 0.f, 0.f};

    // staging indices (fixed per thread)
    const int krow = tid >> 3;           // 0..15
    const int kcol = (tid & 7) * 16;     // 0..112
    const int vr   = (tid >> 4) * 2;     // 0,2,..,14
    const int vc   = (tid & 15) * 4;     // 0..60

    for (int tk = 0; tk < nt; ++tk) {
        const int k0 = tk * 16;

        // ---- stage K tile (row-major f16) and V tile (transposed f16) ----
        {
            const float* kp = K + bo + (size_t)(k0 + krow) * DIM + kcol;
            v4f k0v = *(const v4f*)(kp);
            v4f k1v = *(const v4f*)(kp + 4);
            v4f k2v = *(const v4f*)(kp + 8);
            v4f k3v = *(const v4f*)(kp + 12);
            const float* vp = V + bo + (size_t)(k0 + vr) * DIM + vc;
            v4f va0 = *(const v4f*)(vp);
            v4f va1 = *(const v4f*)(vp + DIM);
            v4f vb0 = *(const v4f*)(vp + 64);
            v4f vb1 = *(const v4f*)(vp + DIM + 64);

            v8h h0, h1;
            #pragma unroll
            for (int i = 0; i < 4; ++i) {
                h0[i]     = (_Float16)k0v[i];
                h0[i + 4] = (_Float16)k1v[i];
                h1[i]     = (_Float16)k2v[i];
                h1[i + 4] = (_Float16)k3v[i];
            }
            *(v8h*)&Ks[krow * 136 + kcol]     = h0;
            *(v8h*)&Ks[krow * 136 + kcol + 8] = h1;

            #pragma unroll
            for (int i = 0; i < 4; ++i) {
                v2h p0 = { (_Float16)va0[i], (_Float16)va1[i] };
                v2h p1 = { (_Float16)vb0[i], (_Float16)vb1[i] };
                *(v2h*)&Vt[(vc + i) * 20 + vr]      = p0;
                *(v2h*)&Vt[(vc + 64 + i) * 20 + vr] = p1;
            }
        }
        __syncthreads();

        if (tk <= my_last) {
            // ---- S^T tile = K * Q^T (16 keys x 16 queries), f32 acc ----
            v4f s = (v4f){0.f, 0.f, 0.f, 0.f};
            #pragma unroll
            for (int dc = 0; dc < 8; ++dc) {
                v4h kf = *(const v4h*)&Ks[n * 136 + dc * 16 + quad * 4];
                s = __builtin_amdgcn_mfma_f32_16x16x16f16(kf, qf[dc], s, 0, 0, 0);
            }
            // causal mask on diagonal tile: key (quad*4+r) > query (n)
            if (tk == my_last) {
                #pragma unroll
                for (int r = 0; r < 4; ++r)
                    if (quad * 4 + r > n) s[r] = -1e30f;
            }
            // online softmax (per lane = per query, replicated across quads)
            float tm = fmaxf(fmaxf(s[0], s[1]), fmaxf(s[2], s[3]));
            tm = fmaxf(tm, __shfl_xor(tm, 16));
            tm = fmaxf(tm, __shfl_xor(tm, 32));
            const float m_new = fmaxf(m_run, tm);
            const float alpha = __expf(m_run - m_new);
            v4f p;
            #pragma unroll
            for (int r = 0; r < 4; ++r) p[r] = __expf(s[r] - m_new);
            float ps = p[0] + p[1] + p[2] + p[3];
            ps += __shfl_xor(ps, 16);
            ps += __shfl_xor(ps, 32);
            l_run = l_run * alpha + ps;
            m_run = m_new;

            // P^T already in B-operand layout: just narrow to f16
            v4h pf;
            #pragma unroll
            for (int r = 0; r < 4; ++r) pf[r] = (_Float16)p[r];

            // ---- O^T += V^T * P^T ----
            #pragma unroll
            for (int dc = 0; dc < 8; ++dc) {
                v4h vf = *(const v4h*)&Vt[(dc * 16 + n) * 20 + quad * 4];
                of[dc] *= alpha;
                of[dc] = __builtin_amdgcn_mfma_f32_16x16x16f16(vf, pf, of[dc], 0, 0, 0);
            }
        }
        __syncthreads();
    }

    // ---- epilogue: O[q0+n][dc*16 + quad*4 + r] = of[dc][r] / l ----
    const float rl = 1.0f / l_run;
    float* op = O + bo + (size_t)(q0 + n) * DIM + quad * 4;
    #pragma unroll
    for (int dc = 0; dc < 8; ++dc) {
        v4f o = of[dc] * rl;
        *(v4f*)(op + dc * 16) = o;
    }
}

extern "C" void kernel_launch(void* const* d_in, const int* in_sizes, int n_in,
                              void* d_out, int out_size, void* d_ws, size_t ws_size,
                              hipStream_t stream) {
    const float* Q = (const float*)d_in[0];
    const float* K = (const float*)d_in[1];
    const float* V = (const float*)d_in[2];
    float* Out = (float*)d_out;
    // 8 batches x 64 q-blocks (32 rows each); batch = blockIdx&7 for XCD L2 locality
    attn_fwd<<<dim3(BATCH * (SEQ / 32)), dim3(128), 0, stream>>>(Q, K, V, Out);
}

// Round 2
// 149.626 us; speedup vs baseline: 1.4642x; 1.4642x over previous
//
#include <hip/hip_runtime.h>

// Causal SDPA, B=8, S=2048, D=128, fp32 in/out. Split-K flash attention:
//   attn_partial: grid over (batch, 32-row q-tile, 512-key chunk); each WG
//     (2 waves, 16 q-rows/wave) runs online softmax over its chunk, writes
//     un-normalized O' + (m,l) to workspace.
//   attn_combine: merges <=4 chunk partials per q-row, normalizes, writes O.
// Layout trick (verified round 1): S^T = K*Q^T C/D layout == B-operand layout
// of O^T += V^T*P^T, so P never leaves registers. Softmax stats per-lane.

#define BATCH 8
#define SEQ   2048
#define DIM   128
#define CK    512
#define NCMAX 4

typedef _Float16 v4h __attribute__((ext_vector_type(4)));
typedef _Float16 v8h __attribute__((ext_vector_type(8)));
typedef float    v4f __attribute__((ext_vector_type(4)));

__global__ __launch_bounds__(128) void attn_partial(
    const float* __restrict__ Q, const float* __restrict__ K,
    const float* __restrict__ V, float* __restrict__ ws)
{
    const int bid   = blockIdx.x;
    const int batch = bid & 7;          // low bits -> XCD spread
    const int qb    = (bid >> 3) & 63;  // 32-row q tile
    const int c     = bid >> 9;         // key chunk 0..3
    if (c > (qb >> 4)) return;          // chunk beyond causal frontier

    const int tid  = threadIdx.x;
    const int wave = tid >> 6;
    const int lane = tid & 63;
    const int n    = lane & 15;
    const int quad = lane >> 4;

    const int q0 = qb * 32 + wave * 16;
    const size_t bo = (size_t)batch * SEQ * DIM;

    const int kbeg = c * CK;
    const int lim  = qb * 32 + 32;
    const int kend = ((c + 1) * CK < lim) ? (c + 1) * CK : lim;

    __shared__ __align__(16) _Float16 Ks[32 * 136];  // keys x d, stride 136
    __shared__ __align__(16) _Float16 Vt[128 * 36];  // d x keys, stride 36

    constexpr float kScale = 0.08838834764831845f;   // 1/sqrt(128)

    // Q fragments (B operand): Q[q0+n][dc*16 + quad*4 + j]
    v4h qf[8];
    {
        const float* qp = Q + bo + (size_t)(q0 + n) * DIM + quad * 4;
        #pragma unroll
        for (int dc = 0; dc < 8; ++dc) {
            v4f qv = *(const v4f*)(qp + dc * 16);
            v4h h;
            #pragma unroll
            for (int i = 0; i < 4; ++i) h[i] = (_Float16)(qv[i] * kScale);
            qf[dc] = h;
        }
    }

    float m_run = -1e30f, l_run = 0.0f;
    v4f of[8];
    #pragma unroll
    for (int dc = 0; dc < 8; ++dc) of[dc] = (v4f){0.f, 0.f, 0.f, 0.f};

    // staging maps (128 threads stage 32x128 K and 32x128 V per iter)
    const int krow = tid >> 2;           // 0..31
    const int kcol = (tid & 3) * 32;     // 0,32,64,96
    const int vr   = (tid >> 4) * 4;     // key rows vr..vr+3
    const int vc   = (tid & 15) * 8;     // d cols vc..vc+7

    v4f kr[8], vv[8];
    {   // prefetch first tile into regs
        const float* kp = K + bo + (size_t)(kbeg + krow) * DIM + kcol;
        #pragma unroll
        for (int i = 0; i < 8; ++i) kr[i] = *(const v4f*)(kp + i * 4);
        const float* vp = V + bo + (size_t)(kbeg + vr) * DIM + vc;
        #pragma unroll
        for (int r = 0; r < 4; ++r) {
            vv[r * 2]     = *(const v4f*)(vp + r * DIM);
            vv[r * 2 + 1] = *(const v4f*)(vp + r * DIM + 4);
        }
    }

    for (int k0 = kbeg; k0 < kend; k0 += 32) {
        // regs -> LDS (f32 -> f16)
        #pragma unroll
        for (int i = 0; i < 4; ++i) {
            v8h h;
            #pragma unroll
            for (int j = 0; j < 4; ++j) {
                h[j]     = (_Float16)kr[i * 2][j];
                h[j + 4] = (_Float16)kr[i * 2 + 1][j];
            }
            *(v8h*)&Ks[krow * 136 + kcol + i * 8] = h;
        }
        #pragma unroll
        for (int i = 0; i < 8; ++i) {
            v4h h;
            #pragma unroll
            for (int r = 0; r < 4; ++r) h[r] = (_Float16)vv[r * 2 + (i >> 2)][i & 3];
            *(v4h*)&Vt[(vc + i) * 36 + vr] = h;
        }
        __syncthreads();

        // prefetch next tile while computing this one
        if (k0 + 32 < kend) {
            const float* kp = K + bo + (size_t)(k0 + 32 + krow) * DIM + kcol;
            #pragma unroll
            for (int i = 0; i < 8; ++i) kr[i] = *(const v4f*)(kp + i * 4);
            const float* vp = V + bo + (size_t)(k0 + 32 + vr) * DIM + vc;
            #pragma unroll
            for (int r = 0; r < 4; ++r) {
                vv[r * 2]     = *(const v4f*)(vp + r * DIM);
                vv[r * 2 + 1] = *(const v4f*)(vp + r * DIM + 4);
            }
        }

        // S^T subtile 0 (keys k0..k0+15)
        v4f s0 = (v4f){0.f, 0.f, 0.f, 0.f};
        #pragma unroll
        for (int dc = 0; dc < 8; ++dc) {
            v4h kf = *(const v4h*)&Ks[n * 136 + dc * 16 + quad * 4];
            s0 = __builtin_amdgcn_mfma_f32_16x16x16f16(kf, qf[dc], s0, 0, 0, 0);
        }
        // S^T subtile 1 (keys k0+16..k0+31), wave-uniform validity
        const bool has1 = (k0 + 16 <= q0);
        v4f s1 = (v4f){0.f, 0.f, 0.f, 0.f};
        if (has1) {
            #pragma unroll
            for (int dc = 0; dc < 8; ++dc) {
                v4h kf = *(const v4h*)&Ks[(16 + n) * 136 + dc * 16 + quad * 4];
                s1 = __builtin_amdgcn_mfma_f32_16x16x16f16(kf, qf[dc], s1, 0, 0, 0);
            }
        }
        if (k0 == q0) {
            #pragma unroll
            for (int r = 0; r < 4; ++r) if (quad * 4 + r > n) s0[r] = -1e30f;
        }
        if (has1 && (k0 + 16 == q0)) {
            #pragma unroll
            for (int r = 0; r < 4; ++r) if (quad * 4 + r > n) s1[r] = -1e30f;
        }

        // online softmax (per lane = per query, replicated across quads)
        float tm = fmaxf(fmaxf(s0[0], s0[1]), fmaxf(s0[2], s0[3]));
        if (has1) tm = fmaxf(tm, fmaxf(fmaxf(s1[0], s1[1]), fmaxf(s1[2], s1[3])));
        tm = fmaxf(tm, __shfl_xor(tm, 16));
        tm = fmaxf(tm, __shfl_xor(tm, 32));
        const float m_new = fmaxf(m_run, tm);
        const float alpha = __expf(m_run - m_new);
        v4h pf0, pf1;
        float ps = 0.f;
        #pragma unroll
        for (int r = 0; r < 4; ++r) {
            float p = __expf(s0[r] - m_new);
            ps += p; pf0[r] = (_Float16)p;
        }
        if (has1) {
            #pragma unroll
            for (int r = 0; r < 4; ++r) {
                float p = __expf(s1[r] - m_new);
                ps += p; pf1[r] = (_Float16)p;
            }
        }
        ps += __shfl_xor(ps, 16);
        ps += __shfl_xor(ps, 32);
        l_run = l_run * alpha + ps;
        m_run = m_new;

        // O^T += V^T * P^T
        #pragma unroll
        for (int dc = 0; dc < 8; ++dc) {
            v4h vf = *(const v4h*)&Vt[(dc * 16 + n) * 36 + quad * 4];
            of[dc] *= alpha;
            of[dc] = __builtin_amdgcn_mfma_f32_16x16x16f16(vf, pf0, of[dc], 0, 0, 0);
        }
        if (has1) {
            #pragma unroll
            for (int dc = 0; dc < 8; ++dc) {
                v4h vf = *(const v4h*)&Vt[(dc * 16 + n) * 36 + 16 + quad * 4];
                of[dc] = __builtin_amdgcn_mfma_f32_16x16x16f16(vf, pf1, of[dc], 0, 0, 0);
            }
        }
        __syncthreads();
    }

    // write un-normalized partial + (m,l)
    float* opart = ws + ((size_t)(c * 8 + batch) * SEQ + q0 + n) * DIM + quad * 4;
    #pragma unroll
    for (int dc = 0; dc < 8; ++dc)
        *(v4f*)(opart + dc * 16) = of[dc];
    if (quad == 0) {
        float* ml = ws + (size_t)NCMAX * 8 * SEQ * DIM
                       + ((size_t)(c * 8 + batch) * SEQ + q0 + n) * 2;
        ml[0] = m_run;
        ml[1] = l_run;
    }
}

__global__ __launch_bounds__(256) void attn_combine(
    const float* __restrict__ ws, float* __restrict__ O)
{
    const int gid = blockIdx.x * 256 + threadIdx.x;
    const size_t e = (size_t)gid * 4;
    const int d = (int)(e & (DIM - 1));
    const int q = (int)((e >> 7) & (SEQ - 1));
    const int b = (int)(e >> 18);
    const int nc = (q >> 9) + 1;        // chunks 0..q>>9 are valid for row q
    const float* ml = ws + (size_t)NCMAX * 8 * SEQ * DIM;
    float mv[NCMAX], lv[NCMAX];
    float M = -1e30f;
    for (int ci = 0; ci < nc; ++ci) {
        const float* p = ml + ((size_t)(ci * 8 + b) * SEQ + q) * 2;
        mv[ci] = p[0]; lv[ci] = p[1];
        M = fmaxf(M, mv[ci]);
    }
    float L = 0.f;
    v4f acc = (v4f){0.f, 0.f, 0.f, 0.f};
    for (int ci = 0; ci < nc; ++ci) {
        const float w = __expf(mv[ci] - M);
        L += lv[ci] * w;
        v4f o = *(const v4f*)(ws + ((size_t)(ci * 8 + b) * SEQ + q) * DIM + d);
        acc += o * w;
    }
    *(v4f*)(O + e) = acc * (1.0f / L);
}

// ---------------- fallback: round-1 monolithic kernel ----------------
__global__ __launch_bounds__(128) void attn_fwd(
    const float* __restrict__ Q, const float* __restrict__ K,
    const float* __restrict__ V, float* __restrict__ O)
{
    const int batch = blockIdx.x & 7;
    const int qb    = blockIdx.x >> 3;
    const int tid   = threadIdx.x;
    const int wave  = tid >> 6;
    const int lane  = tid & 63;
    const int n     = lane & 15;
    const int quad  = lane >> 4;

    const int q0      = qb * 32 + wave * 16;
    const int my_last = qb * 2 + wave;
    const int nt      = qb * 2 + 2;

    const size_t bo = (size_t)batch * SEQ * DIM;

    __shared__ __align__(16) _Float16 Ks[16 * 136];
    __shared__ __align__(16) _Float16 Vt[128 * 20];
    typedef _Float16 v2h __attribute__((ext_vector_type(2)));

    constexpr float kScale = 0.08838834764831845f;

    v4h qf[8];
    {
        const float* qp = Q + bo + (size_t)(q0 + n) * DIM + quad * 4;
        #pragma unroll
        for (int dc = 0; dc < 8; ++dc) {
            v4f qv = *(const v4f*)(qp + dc * 16);
            v4h h;
            #pragma unroll
            for (int i = 0; i < 4; ++i) h[i] = (_Float16)(qv[i] * kScale);
            qf[dc] = h;
        }
    }

    float m_run = -1e30f, l_run = 0.0f;
    v4f of[8];
    #pragma unroll
    for (int dc = 0; dc < 8; ++dc) of[dc] = (v4f){0.f, 0.f, 0.f, 0.f};

    const int krow = tid >> 3;
    const int kcol = (tid & 7) * 16;
    const int vr   = (tid >> 4) * 2;
    const int vc   = (tid & 15) * 4;

    for (int tk = 0; tk < nt; ++tk) {
        const int k0 = tk * 16;
        {
            const float* kp = K + bo + (size_t)(k0 + krow) * DIM + kcol;
            v4f k0v = *(const v4f*)(kp);
            v4f k1v = *(const v4f*)(kp + 4);
            v4f k2v = *(const v4f*)(kp + 8);
            v4f k3v = *(const v4f*)(kp + 12);
            const float* vp = V + bo + (size_t)(k0 + vr) * DIM + vc;
            v4f va0 = *(const v4f*)(vp);
            v4f va1 = *(const v4f*)(vp + DIM);
            v4f vb0 = *(const v4f*)(vp + 64);
            v4f vb1 = *(const v4f*)(vp + DIM + 64);

            v8h h0, h1;
            #pragma unroll
            for (int i = 0; i < 4; ++i) {
                h0[i]     = (_Float16)k0v[i];
                h0[i + 4] = (_Float16)k1v[i];
                h1[i]     = (_Float16)k2v[i];
                h1[i + 4] = (_Float16)k3v[i];
            }
            *(v8h*)&Ks[krow * 136 + kcol]     = h0;
            *(v8h*)&Ks[krow * 136 + kcol + 8] = h1;

            #pragma unroll
            for (int i = 0; i < 4; ++i) {
                v2h p0 = { (_Float16)va0[i], (_Float16)va1[i] };
                v2h p1 = { (_Float16)vb0[i], (_Float16)vb1[i] };
                *(v2h*)&Vt[(vc + i) * 20 + vr]      = p0;
                *(v2h*)&Vt[(vc + 64 + i) * 20 + vr] = p1;
            }
        }
        __syncthreads();

        if (tk <= my_last) {
            v4f s = (v4f){0.f, 0.f, 0.f, 0.f};
            #pragma unroll
            for (int dc = 0; dc < 8; ++dc) {
                v4h kf = *(const v4h*)&Ks[n * 136 + dc * 16 + quad * 4];
                s = __builtin_amdgcn_mfma_f32_16x16x16f16(kf, qf[dc], s, 0, 0, 0);
            }
            if (tk == my_last) {
                #pragma unroll
                for (int r = 0; r < 4; ++r)
                    if (quad * 4 + r > n) s[r] = -1e30f;
            }
            float tm = fmaxf(fmaxf(s[0], s[1]), fmaxf(s[2], s[3]));
            tm = fmaxf(tm, __shfl_xor(tm, 16));
            tm = fmaxf(tm, __shfl_xor(tm, 32));
            const float m_new = fmaxf(m_run, tm);
            const float alpha = __expf(m_run - m_new);
            v4f p;
            #pragma unroll
            for (int r = 0; r < 4; ++r) p[r] = __expf(s[r] - m_new);
            float ps = p[0] + p[1] + p[2] + p[3];
            ps += __shfl_xor(ps, 16);
            ps += __shfl_xor(ps, 32);
            l_run = l_run * alpha + ps;
            m_run = m_new;

            v4h pf;
            #pragma unroll
            for (int r = 0; r < 4; ++r) pf[r] = (_Float16)p[r];

            #pragma unroll
            for (int dc = 0; dc < 8; ++dc) {
                v4h vf = *(const v4h*)&Vt[(dc * 16 + n) * 20 + quad * 4];
                of[dc] *= alpha;
                of[dc] = __builtin_amdgcn_mfma_f32_16x16x16f16(vf, pf, of[dc], 0, 0, 0);
            }
        }
        __syncthreads();
    }

    const float rl = 1.0f / l_run;
    float* op = O + bo + (size_t)(q0 + n) * DIM + quad * 4;
    #pragma unroll
    for (int dc = 0; dc < 8; ++dc) {
        v4f o = of[dc] * rl;
        *(v4f*)(op + dc * 16) = o;
    }
}

extern "C" void kernel_launch(void* const* d_in, const int* in_sizes, int n_in,
                              void* d_out, int out_size, void* d_ws, size_t ws_size,
                              hipStream_t stream) {
    const float* Q = (const float*)d_in[0];
    const float* K = (const float*)d_in[1];
    const float* V = (const float*)d_in[2];
    float* Out = (float*)d_out;

    const size_t need = ((size_t)NCMAX * 8 * SEQ * DIM + (size_t)NCMAX * 8 * SEQ * 2)
                        * sizeof(float);
    if (ws_size >= need) {
        // 8 batches x 64 q-tiles x 4 chunks (invalid chunks early-exit)
        attn_partial<<<dim3(8 * 64 * NCMAX), dim3(128), 0, stream>>>(
            Q, K, V, (float*)d_ws);
        attn_combine<<<dim3(BATCH * SEQ * DIM / 4 / 256), dim3(256), 0, stream>>>(
            (const float*)d_ws, Out);
    } else {
        attn_fwd<<<dim3(BATCH * (SEQ / 32)), dim3(128), 0, stream>>>(Q, K, V, Out);
    }
}